// Round 9
// baseline (515.152 us; speedup 1.0000x reference)
//
#include <hip/hip_runtime.h>

#define T_DIM 1024
#define D_DIM 512
#define M_CODES 2048
#define NT 32768            // 32*1024 query rows
#define TOTAL 16777216      // NT*D_DIM

typedef _Float16 h2 __attribute__((ext_vector_type(2)));
typedef _Float16 h4 __attribute__((ext_vector_type(4)));
typedef _Float16 h8 __attribute__((ext_vector_type(8)));
typedef float f32x4 __attribute__((ext_vector_type(4)));
typedef unsigned int u32;

// ---- workspace layout (bytes) ----
#define WS_MU    0                        // 16384 f32
#define WS_S     65536                    // 16384 f32
#define WS_CZ    131072                   // 32768 f32
#define WS_CE    262144                   // 2048 f32
#define WS_KEYS  270336                   // 32768 u64
#define WS_EH    532480                   // 2048*512 f16
#define WS_EL    (532480 + 2097152)       // 2048*512 f16
#define WS_HIST  (532480 + 4194304)       // 2048 u32
#define WS_LPART (WS_HIST + 8192)         // 8192 f32 per-block loss partials

// async global->LDS, 16B per lane; dst must be wave-uniform (HW adds lane*16)
__device__ __forceinline__ void gload16(const void* g, void* l) {
    __builtin_amdgcn_global_load_lds(
        (const __attribute__((address_space(1))) u32*)g,
        (__attribute__((address_space(3))) u32*)l, 16, 0, 0);
}

__device__ __forceinline__ float block_reduce_sum_256(float v) {
    #pragma unroll
    for (int s = 32; s; s >>= 1) v += __shfl_xor(v, s, 64);
    __shared__ float ls[4];
    int w = threadIdx.x >> 6;
    if ((threadIdx.x & 63) == 0) ls[w] = v;
    __syncthreads();
    float r = (ls[0] + ls[1]) + (ls[2] + ls[3]);
    __syncthreads();
    return r;
}

struct Split { _Float16 hi, lo; };
// v = hi + lo*2^-11 with hi,lo fp16 (lo pre-scaled by 2^11 to stay normal)
__device__ __forceinline__ Split split16(float v) {
    Split r;
    _Float16 h = (_Float16)v;
    float res = v - (float)h;            // exact (Sterbenz)
    r.hi = h;
    r.lo = (_Float16)(res * 2048.0f);    // scale exact
    return r;
}

// ---- instance-norm stats over T per (n,d): mu, s=std+eps ----
__global__ void stats_kernel(const float* __restrict__ x,
                             float* __restrict__ mu_o, float* __restrict__ s_o) {
    int n = blockIdx.y;
    int lane = threadIdx.x & 63;
    int d = blockIdx.x * 64 + lane;
    int tg = threadIdx.x >> 6;
    const float* xp = x + (size_t)n * (T_DIM * D_DIM) + d;
    float sum = 0.f, sq = 0.f;
    int t0 = tg * 256;
    for (int it = 0; it < 256; ++it) {
        float v = xp[(size_t)(t0 + it) * D_DIM];
        sum += v; sq += v * v;
    }
    __shared__ float ssum[4][64], ssq[4][64];
    ssum[tg][lane] = sum;
    ssq[tg][lane] = sq;
    __syncthreads();
    if (threadIdx.x < 64) {
        int l = threadIdx.x;
        float s1 = (ssum[0][l] + ssum[1][l]) + (ssum[2][l] + ssum[3][l]);
        float q1 = (ssq[0][l] + ssq[1][l]) + (ssq[2][l] + ssq[3][l]);
        float mu = s1 * (1.0f / 1024.0f);
        float var = (q1 - 1024.0f * mu * mu) * (1.0f / 1023.0f);
        var = fmaxf(var, 0.0f);
        float sd = sqrtf(var) + 1e-5f;
        int nd = n * D_DIM + blockIdx.x * 64 + l;
        mu_o[nd] = mu; s_o[nd] = sd;
    }
}

// ---- codebook prep: emb_n split to f16 hi/lo, ce = sum(emb_n^2) ----
__global__ void codebook_kernel(const float* __restrict__ emb,
                                _Float16* __restrict__ eh, _Float16* __restrict__ el,
                                float* __restrict__ ce) {
    int j = blockIdx.x;
    int d = threadIdx.x * 2;
    float2 e = *(const float2*)&emb[(size_t)j * D_DIM + d];
    float sq = e.x * e.x + e.y * e.y;
    float norm2 = block_reduce_sum_256(sq);
    float den = sqrtf(norm2) + 1e-4f;
    float en0 = e.x / den, en1 = e.y / den;
    Split s0 = split16(en0), s1 = split16(en1);
    h2 hv, lv;
    hv[0] = s0.hi; hv[1] = s1.hi;
    lv[0] = s0.lo; lv[1] = s1.lo;
    *(h2*)&eh[(size_t)j * D_DIM + d] = hv;
    *(h2*)&el[(size_t)j * D_DIM + d] = lv;
    float cep = en0 * en0 + en1 * en1;
    float cesum = block_reduce_sum_256(cep);
    if (threadIdx.x == 0) ce[j] = cesum;
}

// ---- z = (x-mu)/s exactly like ref; write f16 split + cz = ||z||^2 ----
__global__ void cz_split_kernel(const float* __restrict__ x, const float* __restrict__ mu,
                                const float* __restrict__ s, float* __restrict__ cz,
                                _Float16* __restrict__ zh, _Float16* __restrict__ zl) {
    int i = blockIdx.x * 4 + (threadIdx.x >> 6);
    int lane = threadIdx.x & 63;
    int n = i >> 10;
    const float* xp = x + (size_t)i * D_DIM;
    const float* mp = mu + n * D_DIM;
    const float* sp = s + n * D_DIM;
    float acc = 0.f;
    #pragma unroll
    for (int c = 0; c < 2; ++c) {
        int d = c * 256 + lane * 4;
        float4 xv = *(const float4*)&xp[d];
        float4 mv = *(const float4*)&mp[d];
        float4 sv = *(const float4*)&sp[d];
        float z0 = (xv.x - mv.x) / sv.x;
        float z1 = (xv.y - mv.y) / sv.y;
        float z2 = (xv.z - mv.z) / sv.z;
        float z3 = (xv.w - mv.w) / sv.w;
        Split s0 = split16(z0), s1 = split16(z1), s2 = split16(z2), s3 = split16(z3);
        h4 hv, lv;
        hv[0] = s0.hi; hv[1] = s1.hi; hv[2] = s2.hi; hv[3] = s3.hi;
        lv[0] = s0.lo; lv[1] = s1.lo; lv[2] = s2.lo; lv[3] = s3.lo;
        *(h4*)&zh[(size_t)i * D_DIM + d] = hv;
        *(h4*)&zl[(size_t)i * D_DIM + d] = lv;
        acc += z0 * z0 + z1 * z1 + z2 * z2 + z3 * z3;
    }
    #pragma unroll
    for (int sft = 32; sft; sft >>= 1) acc += __shfl_xor(acc, sft, 64);
    if (lane == 0) cz[i] = acc;
}

// ---- MFMA fp16-split GEMM + argmin, m97 regime: 3 blocks/CU ----
// Tile 128(M)x64(N), BK=32, 4 waves (2Mx2N, 64x32 each), 2 LDS buffers (48KB).
// Swizzle: LDS slot s of row r holds global slot s ^ ((r>>1)&3).
// Buffer layout (h8 units): Ah[512] | Al[512] | Bh[256] | Bl[256] = 1536 (24KB)
__global__ __launch_bounds__(256, 3) void gemm_argmin(
    const _Float16* __restrict__ zh, const _Float16* __restrict__ zl,
    const _Float16* __restrict__ eh, const _Float16* __restrict__ el,
    const float* __restrict__ ce, const float* __restrict__ cz,
    unsigned long long* __restrict__ keys) {
    __shared__ h8 smem[2][1536];
    int tid = threadIdx.x;
    int bid = blockIdx.x;
    int swz = (bid & 7) * 1024 + (bid >> 3);  // XCD-chunked, bijective (8192%8==0)
    int n0 = (swz & 31) * 64;                 // code tile (32 n-tiles)
    int m0 = (swz >> 5) * 128;                // query-row tile (256 m-tiles)

    f32x4 acc0[4][2], acc1[4][2];
    #pragma unroll
    for (int a = 0; a < 4; ++a)
        #pragma unroll
        for (int b = 0; b < 2; ++b) { acc0[a][b] = (f32x4)0.0f; acc1[a][b] = (f32x4)0.0f; }

    int w = tid >> 6, l = tid & 63;
    int wm = (w >> 1) * 64;                   // 2 M-groups of 64
    int wn = (w & 1) * 32;                    // 2 N-groups of 32
    int fr = l & 15, fg = l >> 4;

    // staging geometry, per wave per buffer: 6 gload16
    //  A: rows 32w..32w+31 of Ah and Al (2 q-chunks x {zh,zl})
    //  B: rows 16w..16w+15 of BOTH Bh and Bl (full 64-row coverage by 4 waves)
    int rB = 16 * w + (l >> 2);
    int cB = (((l & 3) ^ ((rB >> 1) & 3)) << 3);
    size_t offB = (size_t)(n0 + rB) * D_DIM + cB;
    int bdst = (16 * w) * 4;

    #define STAGE(buf, kc) do {                                                   \
        _Pragma("unroll")                                                         \
        for (int q = 0; q < 2; ++q) {                                             \
            int rA = 32 * w + 16 * q + (l >> 2);                                  \
            int cA = (((l & 3) ^ ((rA >> 1) & 3)) << 3);                          \
            size_t oa = (size_t)(m0 + rA) * D_DIM + (kc) + cA;                    \
            int db = (32 * w + 16 * q) * 4;                                       \
            gload16(zh + oa, &smem[buf][db]);                                     \
            gload16(zl + oa, &smem[buf][512 + db]);                               \
        }                                                                         \
        gload16(eh + offB + (kc), &smem[buf][1024 + bdst]);                       \
        gload16(el + offB + (kc), &smem[buf][1280 + bdst]);                       \
    } while (0)

    STAGE(0, 0);
    __syncthreads();

    int cur = 0;
    for (int t = 0; t < 16; ++t) {
        if (t < 15) STAGE(cur ^ 1, (t + 1) * 32);
        h8 ah[4], al[4], bh[2], bl[2];
        #pragma unroll
        for (int i = 0; i < 4; ++i) {
            int ra = wm + i * 16 + fr;
            int sa = ra * 4 + (fg ^ ((ra >> 1) & 3));
            ah[i] = smem[cur][sa];
            al[i] = smem[cur][512 + sa];
        }
        #pragma unroll
        for (int i = 0; i < 2; ++i) {
            int rb = wn + i * 16 + fr;
            int sb = rb * 4 + (fg ^ ((rb >> 1) & 3));
            bh[i] = smem[cur][1024 + sb];
            bl[i] = smem[cur][1280 + sb];
        }
        __builtin_amdgcn_s_setprio(1);
        #pragma unroll
        for (int mb = 0; mb < 4; ++mb)
            #pragma unroll
            for (int nb = 0; nb < 2; ++nb) {
                acc0[mb][nb] = __builtin_amdgcn_mfma_f32_16x16x32_f16(ah[mb], bh[nb], acc0[mb][nb], 0, 0, 0);
                acc1[mb][nb] = __builtin_amdgcn_mfma_f32_16x16x32_f16(ah[mb], bl[nb], acc1[mb][nb], 0, 0, 0);
                acc1[mb][nb] = __builtin_amdgcn_mfma_f32_16x16x32_f16(al[mb], bh[nb], acc1[mb][nb], 0, 0, 0);
            }
        __builtin_amdgcn_s_setprio(0);
        __syncthreads();   // drains vmcnt: buf cur^1 staged; cur reads done
        cur ^= 1;
    }
    #undef STAGE

    // epilogue: dist = (ce+cz) - 2*dot, dot = acc0 + acc1*2^-11
    #pragma unroll
    for (int mb = 0; mb < 4; ++mb) {
        #pragma unroll
        for (int r = 0; r < 4; ++r) {
            int q = m0 + wm + mb * 16 + fg * 4 + r;
            float czq = cz[q];
            unsigned long long best = ~0ULL;
            #pragma unroll
            for (int nb = 0; nb < 2; ++nb) {
                int j = n0 + wn + nb * 16 + fr;
                float dotv = acc0[mb][nb][r] + acc1[mb][nb][r] * (1.0f / 2048.0f);
                float dist = (ce[j] + czq) - 2.0f * dotv;
                unsigned long long key =
                    ((unsigned long long)__float_as_uint(dist) << 32) | (unsigned)j;
                if (key < best) best = key;
            }
            #pragma unroll
            for (int sft = 1; sft < 16; sft <<= 1) {
                unsigned long long o = __shfl_xor(best, sft, 64);
                if (o < best) best = o;
            }
            if (fr == 0) atomicMin(keys + q, best);
        }
    }
}

// ---- gather + STE output + loss partials + histogram (1 wave per row) ----
__global__ void output_kernel(const float* __restrict__ x, const float* __restrict__ mu,
                              const float* __restrict__ s, const float* __restrict__ emb,
                              const unsigned long long* __restrict__ keys,
                              float* __restrict__ out, float* __restrict__ loss_part,
                              unsigned* __restrict__ hist) {
    int i = blockIdx.x * 4 + (threadIdx.x >> 6);
    int lane = threadIdx.x & 63;
    int n = i >> 10;
    unsigned idx = (unsigned)(keys[i] & 0xFFFFFFFFULL);
    float lsum = 0.f;
    #pragma unroll
    for (int c = 0; c < 2; ++c) {
        int d = c * 256 + lane * 4;
        float4 xv = *(const float4*)&x[(size_t)i * D_DIM + d];
        float4 mv = *(const float4*)&mu[n * D_DIM + d];
        float4 sv = *(const float4*)&s[n * D_DIM + d];
        float4 ev = *(const float4*)&emb[(size_t)idx * D_DIM + d];
        float z0 = (xv.x - mv.x) / sv.x;
        float z1 = (xv.y - mv.y) / sv.y;
        float z2 = (xv.z - mv.z) / sv.z;
        float z3 = (xv.w - mv.w) / sv.w;
        float o0 = ((z0 + (ev.x - z0)) + ev.x) * 0.5f;
        float o1 = ((z1 + (ev.y - z1)) + ev.y) * 0.5f;
        float o2 = ((z2 + (ev.z - z2)) + ev.z) * 0.5f;
        float o3 = ((z3 + (ev.w - z3)) + ev.w) * 0.5f;
        *(float4*)&out[(size_t)i * D_DIM + d] = make_float4(o0, o1, o2, o3);
        lsum += (z0 - ev.x) * (z0 - ev.x) + (z1 - ev.y) * (z1 - ev.y)
              + (z2 - ev.z) * (z2 - ev.z) + (z3 - ev.w) * (z3 - ev.w);
    }
    #pragma unroll
    for (int sft = 32; sft; sft >>= 1) lsum += __shfl_xor(lsum, sft, 64);
    __shared__ float ls[4];
    if (lane == 0) {
        ls[threadIdx.x >> 6] = lsum;
        atomicAdd(&hist[idx], 1u);   // scattered over 2048 bins: cheap
    }
    __syncthreads();
    if (threadIdx.x == 0)
        loss_part[blockIdx.x] = (ls[0] + ls[1]) + (ls[2] + ls[3]);
}

// ---- scalars: loss mean (from partials) + perplexity ----
__global__ void final_kernel(const unsigned* __restrict__ hist,
                             const float* __restrict__ loss_part, float* __restrict__ out) {
    float h = 0.f;
    for (int b = threadIdx.x; b < M_CODES; b += 256) {
        float p = (float)hist[b] * (1.0f / 32768.0f);
        h += p * logf(p + 1e-10f);
    }
    h = block_reduce_sum_256(h);
    float lsum = 0.f;
    for (int b = threadIdx.x; b < NT / 4; b += 256) lsum += loss_part[b];
    lsum = block_reduce_sum_256(lsum);
    if (threadIdx.x == 0) {
        out[TOTAL] = lsum * (1.0f / 16777216.0f);
        out[TOTAL + 1] = expf(-h);
    }
}

extern "C" void kernel_launch(void* const* d_in, const int* in_sizes, int n_in,
                              void* d_out, int out_size, void* d_ws, size_t ws_size,
                              hipStream_t stream) {
    (void)in_sizes; (void)n_in; (void)out_size; (void)ws_size;
    const float* x = (const float*)d_in[0];
    const float* emb = (const float*)d_in[1];
    float* out = (float*)d_out;
    char* ws = (char*)d_ws;
    float* mu   = (float*)(ws + WS_MU);
    float* s    = (float*)(ws + WS_S);
    float* cz   = (float*)(ws + WS_CZ);
    float* ce   = (float*)(ws + WS_CE);
    unsigned long long* keys = (unsigned long long*)(ws + WS_KEYS);
    _Float16* eh = (_Float16*)(ws + WS_EH);
    _Float16* el = (_Float16*)(ws + WS_EL);
    unsigned* hist = (unsigned*)(ws + WS_HIST);
    float* loss_part = (float*)(ws + WS_LPART);
    // z fp16 split staged in d_out (64MB exactly), overwritten by output_kernel
    _Float16* zh = (_Float16*)d_out;
    _Float16* zl = zh + TOTAL;

    (void)hipMemsetAsync(ws + WS_KEYS, 0xFF, 262144, stream);
    (void)hipMemsetAsync(ws + WS_HIST, 0x00, 8192, stream);

    stats_kernel<<<dim3(8, 32), 256, 0, stream>>>(x, mu, s);
    codebook_kernel<<<M_CODES, 256, 0, stream>>>(emb, eh, el, ce);
    cz_split_kernel<<<NT / 4, 256, 0, stream>>>(x, mu, s, cz, zh, zl);
    gemm_argmin<<<8192, 256, 0, stream>>>(zh, zl, eh, el, ce, cz, keys);
    output_kernel<<<NT / 4, 256, 0, stream>>>(x, mu, s, emb, keys, out, loss_part, hist);
    final_kernel<<<1, 256, 0, stream>>>(hist, loss_part, out);
}

// Round 10
// 269.788 us; speedup vs baseline: 1.9095x; 1.9095x over previous
//
#include <hip/hip_runtime.h>

#define T_DIM 1024
#define D_DIM 512
#define M_CODES 2048
#define NT 32768            // 32*1024 query rows
#define TOTAL 16777216      // NT*D_DIM

typedef _Float16 h2 __attribute__((ext_vector_type(2)));
typedef _Float16 h4 __attribute__((ext_vector_type(4)));
typedef _Float16 h8 __attribute__((ext_vector_type(8)));
typedef float f32x4 __attribute__((ext_vector_type(4)));
typedef unsigned int u32;

// ---- workspace layout (bytes) ----
#define WS_MU    0                        // 16384 f32
#define WS_S     65536                    // 16384 f32
#define WS_CZ    131072                   // 32768 f32
#define WS_CE    262144                   // 2048 f32
#define WS_KEYS  270336                   // 32768 u64
#define WS_EB    532480                   // 2048*512 f16 (single-rounded codebook, 2MB)
#define WS_HIST  (532480 + 2097152)       // 2048 u32
#define WS_LPART (WS_HIST + 8192)         // 8192 f32 per-block loss partials

// async global->LDS, 16B per lane; dst must be wave-uniform (HW adds lane*16)
__device__ __forceinline__ void gload16(const void* g, void* l) {
    __builtin_amdgcn_global_load_lds(
        (const __attribute__((address_space(1))) u32*)g,
        (__attribute__((address_space(3))) u32*)l, 16, 0, 0);
}

__device__ __forceinline__ float block_reduce_sum_256(float v) {
    #pragma unroll
    for (int s = 32; s; s >>= 1) v += __shfl_xor(v, s, 64);
    __shared__ float ls[4];
    int w = threadIdx.x >> 6;
    if ((threadIdx.x & 63) == 0) ls[w] = v;
    __syncthreads();
    float r = (ls[0] + ls[1]) + (ls[2] + ls[3]);
    __syncthreads();
    return r;
}

struct Split { _Float16 hi, lo; };
// v = hi + lo*2^-11 with hi,lo fp16 (lo pre-scaled by 2^11 to stay normal)
__device__ __forceinline__ Split split16(float v) {
    Split r;
    _Float16 h = (_Float16)v;
    float res = v - (float)h;            // exact (Sterbenz)
    r.hi = h;
    r.lo = (_Float16)(res * 2048.0f);    // scale exact
    return r;
}

// ---- instance-norm stats over T per (n,d): mu, s=std+eps ----
__global__ void stats_kernel(const float* __restrict__ x,
                             float* __restrict__ mu_o, float* __restrict__ s_o) {
    int n = blockIdx.y;
    int lane = threadIdx.x & 63;
    int d = blockIdx.x * 64 + lane;
    int tg = threadIdx.x >> 6;
    const float* xp = x + (size_t)n * (T_DIM * D_DIM) + d;
    float sum = 0.f, sq = 0.f;
    int t0 = tg * 256;
    for (int it = 0; it < 256; ++it) {
        float v = xp[(size_t)(t0 + it) * D_DIM];
        sum += v; sq += v * v;
    }
    __shared__ float ssum[4][64], ssq[4][64];
    ssum[tg][lane] = sum;
    ssq[tg][lane] = sq;
    __syncthreads();
    if (threadIdx.x < 64) {
        int l = threadIdx.x;
        float s1 = (ssum[0][l] + ssum[1][l]) + (ssum[2][l] + ssum[3][l]);
        float q1 = (ssq[0][l] + ssq[1][l]) + (ssq[2][l] + ssq[3][l]);
        float mu = s1 * (1.0f / 1024.0f);
        float var = (q1 - 1024.0f * mu * mu) * (1.0f / 1023.0f);
        var = fmaxf(var, 0.0f);
        float sd = sqrtf(var) + 1e-5f;
        int nd = n * D_DIM + blockIdx.x * 64 + l;
        mu_o[nd] = mu; s_o[nd] = sd;
    }
}

// ---- codebook prep: emb_n rounded to f16 (eb), ce = exact sum(emb_n^2) ----
__global__ void codebook_kernel(const float* __restrict__ emb,
                                _Float16* __restrict__ eb, float* __restrict__ ce) {
    int j = blockIdx.x;
    int d = threadIdx.x * 2;
    float2 e = *(const float2*)&emb[(size_t)j * D_DIM + d];
    float sq = e.x * e.x + e.y * e.y;
    float norm2 = block_reduce_sum_256(sq);
    float den = sqrtf(norm2) + 1e-4f;
    float en0 = e.x / den, en1 = e.y / den;
    h2 bv;
    bv[0] = (_Float16)en0;
    bv[1] = (_Float16)en1;
    *(h2*)&eb[(size_t)j * D_DIM + d] = bv;
    float cep = en0 * en0 + en1 * en1;      // ce from EXACT emb_n (matches ref)
    float cesum = block_reduce_sum_256(cep);
    if (threadIdx.x == 0) ce[j] = cesum;
}

// ---- z = (x-mu)/s exactly like ref; write f16 split + cz = ||z||^2 ----
__global__ void cz_split_kernel(const float* __restrict__ x, const float* __restrict__ mu,
                                const float* __restrict__ s, float* __restrict__ cz,
                                _Float16* __restrict__ zh, _Float16* __restrict__ zl) {
    int i = blockIdx.x * 4 + (threadIdx.x >> 6);
    int lane = threadIdx.x & 63;
    int n = i >> 10;
    const float* xp = x + (size_t)i * D_DIM;
    const float* mp = mu + n * D_DIM;
    const float* sp = s + n * D_DIM;
    float acc = 0.f;
    #pragma unroll
    for (int c = 0; c < 2; ++c) {
        int d = c * 256 + lane * 4;
        float4 xv = *(const float4*)&xp[d];
        float4 mv = *(const float4*)&mp[d];
        float4 sv = *(const float4*)&sp[d];
        float z0 = (xv.x - mv.x) / sv.x;
        float z1 = (xv.y - mv.y) / sv.y;
        float z2 = (xv.z - mv.z) / sv.z;
        float z3 = (xv.w - mv.w) / sv.w;
        Split s0 = split16(z0), s1 = split16(z1), s2 = split16(z2), s3 = split16(z3);
        h4 hv, lv;
        hv[0] = s0.hi; hv[1] = s1.hi; hv[2] = s2.hi; hv[3] = s3.hi;
        lv[0] = s0.lo; lv[1] = s1.lo; lv[2] = s2.lo; lv[3] = s3.lo;
        *(h4*)&zh[(size_t)i * D_DIM + d] = hv;
        *(h4*)&zl[(size_t)i * D_DIM + d] = lv;
        acc += z0 * z0 + z1 * z1 + z2 * z2 + z3 * z3;
    }
    #pragma unroll
    for (int sft = 32; sft; sft >>= 1) acc += __shfl_xor(acc, sft, 64);
    if (lane == 0) cz[i] = acc;
}

// ---- MFMA asymmetric-split GEMM + argmin ----
// A = z exact fp16-split (2 passes); B = emb_n rounded to single fp16 (2MB,
// L2-resident per XCD). Tile 128(M)x256(N), BK=32, 8 waves (4Mx2N, 32x128
// each), 2 LDS buffers (64KB). dot = acc0 + acc1*2^-11; dist err ~3e-4 rms
// vs top-2 gaps ~0.4 -> ~tens of index flips, perplexity shift << threshold.
// LDS buffer layout (h8 units): Ah[512] | Al[512] | B[1024] = 2048 (32KB)
// Swizzle: LDS slot s of row r holds global slot s ^ ((r>>1)&3).
__global__ __launch_bounds__(512, 2) void gemm_argmin(
    const _Float16* __restrict__ zh, const _Float16* __restrict__ zl,
    const _Float16* __restrict__ eb,
    const float* __restrict__ ce, const float* __restrict__ cz,
    unsigned long long* __restrict__ keys) {
    __shared__ h8 smem[2][2048];
    int tid = threadIdx.x;
    int bid = blockIdx.x;
    // XCD-chunked (2048%8==0): per XCD, n-tile varies fastest -> 8 consecutive
    // same-XCD blocks reuse one A-tile from L2; full 2MB B resident per XCD.
    int swz = (bid & 7) * 256 + (bid >> 3);
    int n0 = (swz & 7) * 256;                 // code tile (8 n-tiles)
    int m0 = (swz >> 3) * 128;                // query-row tile (256 m-tiles)

    f32x4 acc0[2][8], acc1[2][8];
    #pragma unroll
    for (int a = 0; a < 2; ++a)
        #pragma unroll
        for (int b = 0; b < 8; ++b) { acc0[a][b] = (f32x4)0.0f; acc1[a][b] = (f32x4)0.0f; }

    int w = tid >> 6, l = tid & 63;
    int wm = (w >> 1) * 32;                   // 4 M-groups of 32
    int wn = (w & 1) * 128;                   // 2 N-groups of 128
    int fr = l & 15, fg = l >> 4;

    // staging, per wave per buffer: 4 gload16 (Ah 16 rows, Al 16 rows, B 32 rows)
    int rA = 16 * w + (l >> 2);
    int cA = (((l & 3) ^ ((rA >> 1) & 3)) << 3);
    size_t offA = (size_t)(m0 + rA) * D_DIM + cA;
    int adst = (16 * w) * 4;

    #define STAGE(buf, kc) do {                                                   \
        gload16(zh + offA + (kc), &smem[buf][adst]);                              \
        gload16(zl + offA + (kc), &smem[buf][512 + adst]);                        \
        _Pragma("unroll")                                                         \
        for (int q = 0; q < 2; ++q) {                                             \
            int rB = 32 * w + 16 * q + (l >> 2);                                  \
            int cB = (((l & 3) ^ ((rB >> 1) & 3)) << 3);                          \
            size_t ob = (size_t)(n0 + rB) * D_DIM + (kc) + cB;                    \
            gload16(eb + ob, &smem[buf][1024 + (32 * w + 16 * q) * 4]);           \
        }                                                                         \
    } while (0)

    STAGE(0, 0);
    __syncthreads();

    int cur = 0;
    for (int t = 0; t < 16; ++t) {
        if (t < 15) STAGE(cur ^ 1, (t + 1) * 32);
        h8 ah[2], al[2], bv[8];
        #pragma unroll
        for (int i = 0; i < 2; ++i) {
            int ra = wm + i * 16 + fr;
            int sa = ra * 4 + (fg ^ ((ra >> 1) & 3));
            ah[i] = smem[cur][sa];
            al[i] = smem[cur][512 + sa];
        }
        #pragma unroll
        for (int i = 0; i < 8; ++i) {
            int rb = wn + i * 16 + fr;
            int sb = rb * 4 + (fg ^ ((rb >> 1) & 3));
            bv[i] = smem[cur][1024 + sb];
        }
        __builtin_amdgcn_s_setprio(1);
        #pragma unroll
        for (int mb = 0; mb < 2; ++mb)
            #pragma unroll
            for (int nb = 0; nb < 8; ++nb) {
                acc0[mb][nb] = __builtin_amdgcn_mfma_f32_16x16x32_f16(ah[mb], bv[nb], acc0[mb][nb], 0, 0, 0);
                acc1[mb][nb] = __builtin_amdgcn_mfma_f32_16x16x32_f16(al[mb], bv[nb], acc1[mb][nb], 0, 0, 0);
            }
        __builtin_amdgcn_s_setprio(0);
        __syncthreads();   // drains vmcnt: buf cur^1 staged; cur reads done
        cur ^= 1;
    }
    #undef STAGE

    // epilogue: dist = (ce+cz) - 2*dot, dot = acc0 + acc1*2^-11
    #pragma unroll
    for (int mb = 0; mb < 2; ++mb) {
        #pragma unroll
        for (int r = 0; r < 4; ++r) {
            int q = m0 + wm + mb * 16 + fg * 4 + r;
            float czq = cz[q];
            unsigned long long best = ~0ULL;
            #pragma unroll
            for (int nb = 0; nb < 8; ++nb) {
                int j = n0 + wn + nb * 16 + fr;
                float dotv = acc0[mb][nb][r] + acc1[mb][nb][r] * (1.0f / 2048.0f);
                float dist = (ce[j] + czq) - 2.0f * dotv;
                unsigned long long key =
                    ((unsigned long long)__float_as_uint(dist) << 32) | (unsigned)j;
                if (key < best) best = key;
            }
            #pragma unroll
            for (int sft = 1; sft < 16; sft <<= 1) {
                unsigned long long o = __shfl_xor(best, sft, 64);
                if (o < best) best = o;
            }
            if (fr == 0) atomicMin(keys + q, best);
        }
    }
}

// ---- gather + STE output + loss partials + histogram (1 wave per row) ----
__global__ void output_kernel(const float* __restrict__ x, const float* __restrict__ mu,
                              const float* __restrict__ s, const float* __restrict__ emb,
                              const unsigned long long* __restrict__ keys,
                              float* __restrict__ out, float* __restrict__ loss_part,
                              unsigned* __restrict__ hist) {
    int i = blockIdx.x * 4 + (threadIdx.x >> 6);
    int lane = threadIdx.x & 63;
    int n = i >> 10;
    unsigned idx = (unsigned)(keys[i] & 0xFFFFFFFFULL);
    float lsum = 0.f;
    #pragma unroll
    for (int c = 0; c < 2; ++c) {
        int d = c * 256 + lane * 4;
        float4 xv = *(const float4*)&x[(size_t)i * D_DIM + d];
        float4 mv = *(const float4*)&mu[n * D_DIM + d];
        float4 sv = *(const float4*)&s[n * D_DIM + d];
        float4 ev = *(const float4*)&emb[(size_t)idx * D_DIM + d];
        float z0 = (xv.x - mv.x) / sv.x;
        float z1 = (xv.y - mv.y) / sv.y;
        float z2 = (xv.z - mv.z) / sv.z;
        float z3 = (xv.w - mv.w) / sv.w;
        float o0 = ((z0 + (ev.x - z0)) + ev.x) * 0.5f;
        float o1 = ((z1 + (ev.y - z1)) + ev.y) * 0.5f;
        float o2 = ((z2 + (ev.z - z2)) + ev.z) * 0.5f;
        float o3 = ((z3 + (ev.w - z3)) + ev.w) * 0.5f;
        *(float4*)&out[(size_t)i * D_DIM + d] = make_float4(o0, o1, o2, o3);
        lsum += (z0 - ev.x) * (z0 - ev.x) + (z1 - ev.y) * (z1 - ev.y)
              + (z2 - ev.z) * (z2 - ev.z) + (z3 - ev.w) * (z3 - ev.w);
    }
    #pragma unroll
    for (int sft = 32; sft; sft >>= 1) lsum += __shfl_xor(lsum, sft, 64);
    __shared__ float ls[4];
    if (lane == 0) {
        ls[threadIdx.x >> 6] = lsum;
        atomicAdd(&hist[idx], 1u);   // scattered over 2048 bins: cheap
    }
    __syncthreads();
    if (threadIdx.x == 0)
        loss_part[blockIdx.x] = (ls[0] + ls[1]) + (ls[2] + ls[3]);
}

// ---- scalars: loss mean (from partials) + perplexity ----
__global__ void final_kernel(const unsigned* __restrict__ hist,
                             const float* __restrict__ loss_part, float* __restrict__ out) {
    float h = 0.f;
    for (int b = threadIdx.x; b < M_CODES; b += 256) {
        float p = (float)hist[b] * (1.0f / 32768.0f);
        h += p * logf(p + 1e-10f);
    }
    h = block_reduce_sum_256(h);
    float lsum = 0.f;
    for (int b = threadIdx.x; b < NT / 4; b += 256) lsum += loss_part[b];
    lsum = block_reduce_sum_256(lsum);
    if (threadIdx.x == 0) {
        out[TOTAL] = lsum * (1.0f / 16777216.0f);
        out[TOTAL + 1] = expf(-h);
    }
}

extern "C" void kernel_launch(void* const* d_in, const int* in_sizes, int n_in,
                              void* d_out, int out_size, void* d_ws, size_t ws_size,
                              hipStream_t stream) {
    (void)in_sizes; (void)n_in; (void)out_size; (void)ws_size;
    const float* x = (const float*)d_in[0];
    const float* emb = (const float*)d_in[1];
    float* out = (float*)d_out;
    char* ws = (char*)d_ws;
    float* mu   = (float*)(ws + WS_MU);
    float* s    = (float*)(ws + WS_S);
    float* cz   = (float*)(ws + WS_CZ);
    float* ce   = (float*)(ws + WS_CE);
    unsigned long long* keys = (unsigned long long*)(ws + WS_KEYS);
    _Float16* eb = (_Float16*)(ws + WS_EB);
    unsigned* hist = (unsigned*)(ws + WS_HIST);
    float* loss_part = (float*)(ws + WS_LPART);
    // z fp16 split staged in d_out (64MB exactly), overwritten by output_kernel
    _Float16* zh = (_Float16*)d_out;
    _Float16* zl = zh + TOTAL;

    (void)hipMemsetAsync(ws + WS_KEYS, 0xFF, 262144, stream);
    (void)hipMemsetAsync(ws + WS_HIST, 0x00, 8192, stream);

    stats_kernel<<<dim3(8, 32), 256, 0, stream>>>(x, mu, s);
    codebook_kernel<<<M_CODES, 256, 0, stream>>>(emb, eb, ce);
    cz_split_kernel<<<NT / 4, 256, 0, stream>>>(x, mu, s, cz, zh, zl);
    gemm_argmin<<<2048, 512, 0, stream>>>(zh, zl, eb, ce, cz, keys);
    output_kernel<<<NT / 4, 256, 0, stream>>>(x, mu, s, emb, keys, out, loss_part, hist);
    final_kernel<<<1, 256, 0, stream>>>(hist, loss_part, out);
}

// Round 11
// 181.504 us; speedup vs baseline: 2.8382x; 1.4864x over previous
//
#include <hip/hip_runtime.h>

#define T_DIM 1024
#define D_DIM 512
#define M_CODES 2048
#define NT 32768            // 32*1024 query rows
#define TOTAL 16777216      // NT*D_DIM

typedef _Float16 h2 __attribute__((ext_vector_type(2)));
typedef _Float16 h4 __attribute__((ext_vector_type(4)));
typedef _Float16 h8 __attribute__((ext_vector_type(8)));
typedef float f32x4 __attribute__((ext_vector_type(4)));
typedef unsigned int u32;

// ---- workspace layout (bytes) ----
#define WS_MU    0                        // 16384 f32
#define WS_S     65536                    // 16384 f32
#define WS_CZ    131072                   // 32768 f32
#define WS_CE    262144                   // 2048 f32
#define WS_KEYS  270336                   // 32768 u64
#define WS_EB    532480                   // 2048*512 f16 (rounded codebook, 2MB)
#define WS_HIST  (532480 + 2097152)       // 2048 u32
#define WS_LPART (WS_HIST + 8192)         // 8192 f32 per-block loss partials

// async global->LDS, 16B per lane; dst must be wave-uniform (HW adds lane*16)
__device__ __forceinline__ void gload16(const void* g, void* l) {
    __builtin_amdgcn_global_load_lds(
        (const __attribute__((address_space(1))) u32*)g,
        (__attribute__((address_space(3))) u32*)l, 16, 0, 0);
}

__device__ __forceinline__ float block_reduce_sum_256(float v) {
    #pragma unroll
    for (int s = 32; s; s >>= 1) v += __shfl_xor(v, s, 64);
    __shared__ float ls[4];
    int w = threadIdx.x >> 6;
    if ((threadIdx.x & 63) == 0) ls[w] = v;
    __syncthreads();
    float r = (ls[0] + ls[1]) + (ls[2] + ls[3]);
    __syncthreads();
    return r;
}

// ---- instance-norm stats over T per (n,d): mu, s=std+eps ----
__global__ void stats_kernel(const float* __restrict__ x,
                             float* __restrict__ mu_o, float* __restrict__ s_o) {
    int n = blockIdx.y;
    int lane = threadIdx.x & 63;
    int d = blockIdx.x * 64 + lane;
    int tg = threadIdx.x >> 6;
    const float* xp = x + (size_t)n * (T_DIM * D_DIM) + d;
    float sum = 0.f, sq = 0.f;
    int t0 = tg * 256;
    for (int it = 0; it < 256; ++it) {
        float v = xp[(size_t)(t0 + it) * D_DIM];
        sum += v; sq += v * v;
    }
    __shared__ float ssum[4][64], ssq[4][64];
    ssum[tg][lane] = sum;
    ssq[tg][lane] = sq;
    __syncthreads();
    if (threadIdx.x < 64) {
        int l = threadIdx.x;
        float s1 = (ssum[0][l] + ssum[1][l]) + (ssum[2][l] + ssum[3][l]);
        float q1 = (ssq[0][l] + ssq[1][l]) + (ssq[2][l] + ssq[3][l]);
        float mu = s1 * (1.0f / 1024.0f);
        float var = (q1 - 1024.0f * mu * mu) * (1.0f / 1023.0f);
        var = fmaxf(var, 0.0f);
        float sd = sqrtf(var) + 1e-5f;
        int nd = n * D_DIM + blockIdx.x * 64 + l;
        mu_o[nd] = mu; s_o[nd] = sd;
    }
}

// ---- codebook prep: emb_n rounded to f16 (eb), ce = exact sum(emb_n^2) ----
__global__ void codebook_kernel(const float* __restrict__ emb,
                                _Float16* __restrict__ eb, float* __restrict__ ce) {
    int j = blockIdx.x;
    int d = threadIdx.x * 2;
    float2 e = *(const float2*)&emb[(size_t)j * D_DIM + d];
    float sq = e.x * e.x + e.y * e.y;
    float norm2 = block_reduce_sum_256(sq);
    float den = sqrtf(norm2) + 1e-4f;
    float en0 = e.x / den, en1 = e.y / den;
    h2 bv;
    bv[0] = (_Float16)en0;
    bv[1] = (_Float16)en1;
    *(h2*)&eb[(size_t)j * D_DIM + d] = bv;
    float cep = en0 * en0 + en1 * en1;      // ce from EXACT emb_n (matches ref)
    float cesum = block_reduce_sum_256(cep);
    if (threadIdx.x == 0) ce[j] = cesum;
}

// ---- z = (x-mu)/s exact in fp32; store z rounded to fp16; cz = exact ||z||^2 ----
__global__ void cz_split_kernel(const float* __restrict__ x, const float* __restrict__ mu,
                                const float* __restrict__ s, float* __restrict__ cz,
                                _Float16* __restrict__ zh) {
    int i = blockIdx.x * 4 + (threadIdx.x >> 6);
    int lane = threadIdx.x & 63;
    int n = i >> 10;
    const float* xp = x + (size_t)i * D_DIM;
    const float* mp = mu + n * D_DIM;
    const float* sp = s + n * D_DIM;
    float acc = 0.f;
    #pragma unroll
    for (int c = 0; c < 2; ++c) {
        int d = c * 256 + lane * 4;
        float4 xv = *(const float4*)&xp[d];
        float4 mv = *(const float4*)&mp[d];
        float4 sv = *(const float4*)&sp[d];
        float z0 = (xv.x - mv.x) / sv.x;
        float z1 = (xv.y - mv.y) / sv.y;
        float z2 = (xv.z - mv.z) / sv.z;
        float z3 = (xv.w - mv.w) / sv.w;
        h4 hv;
        hv[0] = (_Float16)z0; hv[1] = (_Float16)z1;
        hv[2] = (_Float16)z2; hv[3] = (_Float16)z3;
        *(h4*)&zh[(size_t)i * D_DIM + d] = hv;
        acc += z0 * z0 + z1 * z1 + z2 * z2 + z3 * z3;   // cz stays exact
    }
    #pragma unroll
    for (int sft = 32; sft; sft >>= 1) acc += __shfl_xor(acc, sft, 64);
    if (lane == 0) cz[i] = acc;
}

// ---- MFMA single-fp16 GEMM + argmin ----
// A = z fp16, B = emb_n fp16 (both rounded; cz/ce exact fp32). Single pass.
// Tile 256(M)x256(N), BK=32, 8 waves (4Mx2N, 64x128 each), 2 LDS bufs (64KB).
// Staged traffic: A 32MB*8 + B 2MB*128 = 512MB @ ~6TB/s staging ceiling.
// LDS buffer (h8 units): A[1024] | B[1024]; slot s of row r holds global
// slot s ^ ((r>>1)&3) (zero-conflict, verified R5-R10).
__global__ __launch_bounds__(512, 2) void gemm_argmin(
    const _Float16* __restrict__ zh, const _Float16* __restrict__ eb,
    const float* __restrict__ ce, const float* __restrict__ cz,
    unsigned long long* __restrict__ keys) {
    __shared__ h8 smem[2][2048];
    int tid = threadIdx.x;
    int bid = blockIdx.x;
    // XCD-chunked (1024%8==0): per XCD n varies fastest -> A-tile reused by 8
    // consecutive same-XCD blocks; full 2MB B L2-resident per XCD.
    int swz = (bid & 7) * 128 + (bid >> 3);
    int n0 = (swz & 7) * 256;                 // code tile (8 n-tiles)
    int m0 = (swz >> 3) * 256;                // query-row tile (128 m-tiles)

    f32x4 acc[4][8];
    #pragma unroll
    for (int a = 0; a < 4; ++a)
        #pragma unroll
        for (int b = 0; b < 8; ++b) acc[a][b] = (f32x4)0.0f;

    int w = tid >> 6, l = tid & 63;
    int wm = (w >> 1) * 64;                   // 4 M-groups of 64
    int wn = (w & 1) * 128;                   // 2 N-groups of 128
    int fr = l & 15, fg = l >> 4;

    // staging, per wave per buffer: 4 gload16 (A rows 32w..32w+31, B same rows)
    #define STAGE(buf, kc) do {                                                   \
        _Pragma("unroll")                                                         \
        for (int q = 0; q < 2; ++q) {                                             \
            int r = 32 * w + 16 * q + (l >> 2);                                   \
            int c = (((l & 3) ^ ((r >> 1) & 3)) << 3);                            \
            int db = (32 * w + 16 * q) * 4;                                       \
            gload16(zh + (size_t)(m0 + r) * D_DIM + (kc) + c, &smem[buf][db]);    \
            gload16(eb + (size_t)(n0 + r) * D_DIM + (kc) + c,                     \
                    &smem[buf][1024 + db]);                                       \
        }                                                                         \
    } while (0)

    STAGE(0, 0);
    __syncthreads();

    int cur = 0;
    for (int t = 0; t < 16; ++t) {
        if (t < 15) STAGE(cur ^ 1, (t + 1) * 32);
        h8 av[4], bv[8];
        #pragma unroll
        for (int i = 0; i < 4; ++i) {
            int ra = wm + i * 16 + fr;
            av[i] = smem[cur][ra * 4 + (fg ^ ((ra >> 1) & 3))];
        }
        #pragma unroll
        for (int j = 0; j < 8; ++j) {
            int rb = wn + j * 16 + fr;
            bv[j] = smem[cur][1024 + rb * 4 + (fg ^ ((rb >> 1) & 3))];
        }
        __builtin_amdgcn_s_setprio(1);
        #pragma unroll
        for (int mb = 0; mb < 4; ++mb)
            #pragma unroll
            for (int nb = 0; nb < 8; ++nb)
                acc[mb][nb] = __builtin_amdgcn_mfma_f32_16x16x32_f16(av[mb], bv[nb], acc[mb][nb], 0, 0, 0);
        __builtin_amdgcn_s_setprio(0);
        __syncthreads();   // drains vmcnt: buf cur^1 staged; cur reads done
        cur ^= 1;
    }
    #undef STAGE

    // epilogue: dist = (ce+cz) - 2*dot
    #pragma unroll
    for (int mb = 0; mb < 4; ++mb) {
        #pragma unroll
        for (int r = 0; r < 4; ++r) {
            int q = m0 + wm + mb * 16 + fg * 4 + r;
            float czq = cz[q];
            unsigned long long best = ~0ULL;
            #pragma unroll
            for (int nb = 0; nb < 8; ++nb) {
                int j = n0 + wn + nb * 16 + fr;
                float dist = (ce[j] + czq) - 2.0f * acc[mb][nb][r];
                unsigned long long key =
                    ((unsigned long long)__float_as_uint(dist) << 32) | (unsigned)j;
                if (key < best) best = key;
            }
            #pragma unroll
            for (int sft = 1; sft < 16; sft <<= 1) {
                unsigned long long o = __shfl_xor(best, sft, 64);
                if (o < best) best = o;
            }
            if (fr == 0) atomicMin(keys + q, best);
        }
    }
}

// ---- gather + STE output + loss partials + histogram (1 wave per row) ----
__global__ void output_kernel(const float* __restrict__ x, const float* __restrict__ mu,
                              const float* __restrict__ s, const float* __restrict__ emb,
                              const unsigned long long* __restrict__ keys,
                              float* __restrict__ out, float* __restrict__ loss_part,
                              unsigned* __restrict__ hist) {
    int i = blockIdx.x * 4 + (threadIdx.x >> 6);
    int lane = threadIdx.x & 63;
    int n = i >> 10;
    unsigned idx = (unsigned)(keys[i] & 0xFFFFFFFFULL);
    float lsum = 0.f;
    #pragma unroll
    for (int c = 0; c < 2; ++c) {
        int d = c * 256 + lane * 4;
        float4 xv = *(const float4*)&x[(size_t)i * D_DIM + d];
        float4 mv = *(const float4*)&mu[n * D_DIM + d];
        float4 sv = *(const float4*)&s[n * D_DIM + d];
        float4 ev = *(const float4*)&emb[(size_t)idx * D_DIM + d];
        float z0 = (xv.x - mv.x) / sv.x;
        float z1 = (xv.y - mv.y) / sv.y;
        float z2 = (xv.z - mv.z) / sv.z;
        float z3 = (xv.w - mv.w) / sv.w;
        float o0 = ((z0 + (ev.x - z0)) + ev.x) * 0.5f;
        float o1 = ((z1 + (ev.y - z1)) + ev.y) * 0.5f;
        float o2 = ((z2 + (ev.z - z2)) + ev.z) * 0.5f;
        float o3 = ((z3 + (ev.w - z3)) + ev.w) * 0.5f;
        *(float4*)&out[(size_t)i * D_DIM + d] = make_float4(o0, o1, o2, o3);
        lsum += (z0 - ev.x) * (z0 - ev.x) + (z1 - ev.y) * (z1 - ev.y)
              + (z2 - ev.z) * (z2 - ev.z) + (z3 - ev.w) * (z3 - ev.w);
    }
    #pragma unroll
    for (int sft = 32; sft; sft >>= 1) lsum += __shfl_xor(lsum, sft, 64);
    __shared__ float ls[4];
    if (lane == 0) {
        ls[threadIdx.x >> 6] = lsum;
        atomicAdd(&hist[idx], 1u);   // scattered over 2048 bins: cheap
    }
    __syncthreads();
    if (threadIdx.x == 0)
        loss_part[blockIdx.x] = (ls[0] + ls[1]) + (ls[2] + ls[3]);
}

// ---- scalars: loss mean (from partials) + perplexity ----
__global__ void final_kernel(const unsigned* __restrict__ hist,
                             const float* __restrict__ loss_part, float* __restrict__ out) {
    float h = 0.f;
    for (int b = threadIdx.x; b < M_CODES; b += 256) {
        float p = (float)hist[b] * (1.0f / 32768.0f);
        h += p * logf(p + 1e-10f);
    }
    h = block_reduce_sum_256(h);
    float lsum = 0.f;
    for (int b = threadIdx.x; b < NT / 4; b += 256) lsum += loss_part[b];
    lsum = block_reduce_sum_256(lsum);
    if (threadIdx.x == 0) {
        out[TOTAL] = lsum * (1.0f / 16777216.0f);
        out[TOTAL + 1] = expf(-h);
    }
}

extern "C" void kernel_launch(void* const* d_in, const int* in_sizes, int n_in,
                              void* d_out, int out_size, void* d_ws, size_t ws_size,
                              hipStream_t stream) {
    (void)in_sizes; (void)n_in; (void)out_size; (void)ws_size;
    const float* x = (const float*)d_in[0];
    const float* emb = (const float*)d_in[1];
    float* out = (float*)d_out;
    char* ws = (char*)d_ws;
    float* mu   = (float*)(ws + WS_MU);
    float* s    = (float*)(ws + WS_S);
    float* cz   = (float*)(ws + WS_CZ);
    float* ce   = (float*)(ws + WS_CE);
    unsigned long long* keys = (unsigned long long*)(ws + WS_KEYS);
    _Float16* eb = (_Float16*)(ws + WS_EB);
    unsigned* hist = (unsigned*)(ws + WS_HIST);
    float* loss_part = (float*)(ws + WS_LPART);
    // z fp16 staged in d_out (32MB), overwritten by output_kernel
    _Float16* zh = (_Float16*)d_out;

    (void)hipMemsetAsync(ws + WS_KEYS, 0xFF, 262144, stream);
    (void)hipMemsetAsync(ws + WS_HIST, 0x00, 8192, stream);

    stats_kernel<<<dim3(8, 32), 256, 0, stream>>>(x, mu, s);
    codebook_kernel<<<M_CODES, 256, 0, stream>>>(emb, eb, ce);
    cz_split_kernel<<<NT / 4, 256, 0, stream>>>(x, mu, s, cz, zh);
    gemm_argmin<<<1024, 512, 0, stream>>>(zh, eb, ce, cz, keys);
    output_kernel<<<NT / 4, 256, 0, stream>>>(x, mu, s, emb, keys, out, loss_part, hist);
    final_kernel<<<1, 256, 0, stream>>>(hist, loss_part, out);
}

// Round 12
// 169.113 us; speedup vs baseline: 3.0462x; 1.0733x over previous
//
#include <hip/hip_runtime.h>

#define T_DIM 1024
#define D_DIM 512
#define M_CODES 2048
#define NT 32768            // 32*1024 query rows
#define TOTAL 16777216      // NT*D_DIM

typedef _Float16 h2 __attribute__((ext_vector_type(2)));
typedef float f32x4 __attribute__((ext_vector_type(4)));
typedef unsigned int u32;

// ---- workspace layout (bytes) ----
#define WS_MU    0                        // 16384 f32
#define WS_S     65536                    // 16384 f32
#define WS_CZ    131072                   // 32768 f32
#define WS_CE    262144                   // 2048 f32
#define WS_KEYS  270336                   // 32768 u64
#define WS_EB    532480                   // 2048*512 fp8 (rounded codebook, 1MB)
#define WS_HIST  (532480 + 1048576)       // 2048 u32
#define WS_LPART (WS_HIST + 8192)         // 8192 f32 per-block loss partials

// async global->LDS, 16B per lane; dst must be wave-uniform (HW adds lane*16)
__device__ __forceinline__ void gload16(const void* g, void* l) {
    __builtin_amdgcn_global_load_lds(
        (const __attribute__((address_space(1))) u32*)g,
        (__attribute__((address_space(3))) u32*)l, 16, 0, 0);
}

__device__ __forceinline__ float block_reduce_sum_256(float v) {
    #pragma unroll
    for (int s = 32; s; s >>= 1) v += __shfl_xor(v, s, 64);
    __shared__ float ls[4];
    int w = threadIdx.x >> 6;
    if ((threadIdx.x & 63) == 0) ls[w] = v;
    __syncthreads();
    float r = (ls[0] + ls[1]) + (ls[2] + ls[3]);
    __syncthreads();
    return r;
}

// pack 4 floats -> 4 fp8 e4m3 (OCP, RNE)
__device__ __forceinline__ u32 pk_fp8x4(float a, float b, float c, float d) {
    u32 w = __builtin_amdgcn_cvt_pk_fp8_f32(a, b, 0, false);
    w = __builtin_amdgcn_cvt_pk_fp8_f32(c, d, w, true);
    return w;
}

// ---- instance-norm stats over T per (n,d): mu, s=std+eps ----
__global__ void stats_kernel(const float* __restrict__ x,
                             float* __restrict__ mu_o, float* __restrict__ s_o) {
    int n = blockIdx.y;
    int lane = threadIdx.x & 63;
    int d = blockIdx.x * 64 + lane;
    int tg = threadIdx.x >> 6;
    const float* xp = x + (size_t)n * (T_DIM * D_DIM) + d;
    float sum = 0.f, sq = 0.f;
    int t0 = tg * 256;
    for (int it = 0; it < 256; ++it) {
        float v = xp[(size_t)(t0 + it) * D_DIM];
        sum += v; sq += v * v;
    }
    __shared__ float ssum[4][64], ssq[4][64];
    ssum[tg][lane] = sum;
    ssq[tg][lane] = sq;
    __syncthreads();
    if (threadIdx.x < 64) {
        int l = threadIdx.x;
        float s1 = (ssum[0][l] + ssum[1][l]) + (ssum[2][l] + ssum[3][l]);
        float q1 = (ssq[0][l] + ssq[1][l]) + (ssq[2][l] + ssq[3][l]);
        float mu = s1 * (1.0f / 1024.0f);
        float var = (q1 - 1024.0f * mu * mu) * (1.0f / 1023.0f);
        var = fmaxf(var, 0.0f);
        float sd = sqrtf(var) + 1e-5f;
        int nd = n * D_DIM + blockIdx.x * 64 + l;
        mu_o[nd] = mu; s_o[nd] = sd;
    }
}

// ---- codebook prep: emb_n rounded to fp8 (eb), ce = exact sum(emb_n^2) ----
__global__ void codebook_kernel(const float* __restrict__ emb,
                                unsigned char* __restrict__ eb, float* __restrict__ ce) {
    int j = blockIdx.x;
    int d = threadIdx.x * 2;
    float2 e = *(const float2*)&emb[(size_t)j * D_DIM + d];
    float sq = e.x * e.x + e.y * e.y;
    float norm2 = block_reduce_sum_256(sq);
    float den = sqrtf(norm2) + 1e-4f;
    float en0 = e.x / den, en1 = e.y / den;
    u32 w = __builtin_amdgcn_cvt_pk_fp8_f32(en0, en1, 0, false);
    *(unsigned short*)&eb[(size_t)j * D_DIM + d] = (unsigned short)(w & 0xFFFF);
    float cep = en0 * en0 + en1 * en1;      // ce from EXACT emb_n (matches ref)
    float cesum = block_reduce_sum_256(cep);
    if (threadIdx.x == 0) ce[j] = cesum;
}

// ---- z = (x-mu)/s exact fp32; store z as fp8; cz = exact ||z||^2 ----
__global__ void cz_split_kernel(const float* __restrict__ x, const float* __restrict__ mu,
                                const float* __restrict__ s, float* __restrict__ cz,
                                unsigned char* __restrict__ zq) {
    int i = blockIdx.x * 4 + (threadIdx.x >> 6);
    int lane = threadIdx.x & 63;
    int n = i >> 10;
    const float* xp = x + (size_t)i * D_DIM;
    const float* mp = mu + n * D_DIM;
    const float* sp = s + n * D_DIM;
    float acc = 0.f;
    #pragma unroll
    for (int c = 0; c < 2; ++c) {
        int d = c * 256 + lane * 4;
        float4 xv = *(const float4*)&xp[d];
        float4 mv = *(const float4*)&mp[d];
        float4 sv = *(const float4*)&sp[d];
        float z0 = (xv.x - mv.x) / sv.x;
        float z1 = (xv.y - mv.y) / sv.y;
        float z2 = (xv.z - mv.z) / sv.z;
        float z3 = (xv.w - mv.w) / sv.w;
        *(u32*)&zq[(size_t)i * D_DIM + d] = pk_fp8x4(z0, z1, z2, z3);
        acc += z0 * z0 + z1 * z1 + z2 * z2 + z3 * z3;   // cz stays exact
    }
    #pragma unroll
    for (int sft = 32; sft; sft >>= 1) acc += __shfl_xor(acc, sft, 64);
    if (lane == 0) cz[i] = acc;
}

// ---- MFMA fp8 GEMM + argmin ----
// A = z fp8 e4m3, B = emb_n fp8 e4m3 (cz/ce exact fp32). Staged traffic:
// A 16MB*8 + B 1MB*128 = 256MB @ ~5TB/s staging ceiling.
// Tile 256(M)x256(N), BK=64 (64B/row/step), 8 waves (4Mx2N), 2 LDS bufs 64KB.
// LDS (u64 units): A[2048] | B[2048]. Row = 64B = 4 16B-slots; stored slot
// s' = s ^ ((r>>1)&3) (same involution on stage source and read — R5-R11).
// Fragment (k-half h, lane fr,fg): slot s = (2h+(fg>>1))^((r>>1)&3),
// u64 index = r*8 + s*2 + (fg&1). Word-level bank spread is exactly even.
__global__ __launch_bounds__(512, 2) void gemm_argmin(
    const unsigned char* __restrict__ zq, const unsigned char* __restrict__ eb,
    const float* __restrict__ ce, const float* __restrict__ cz,
    unsigned long long* __restrict__ keys) {
    __shared__ long smem[2][4096];
    int tid = threadIdx.x;
    int bid = blockIdx.x;
    // XCD-chunked (1024%8==0): per XCD n varies fastest -> A-tile L2 reuse.
    int swz = (bid & 7) * 128 + (bid >> 3);
    int n0 = (swz & 7) * 256;                 // code tile (8 n-tiles)
    int m0 = (swz >> 3) * 256;                // query-row tile (128 m-tiles)

    f32x4 acc[4][8];
    #pragma unroll
    for (int a = 0; a < 4; ++a)
        #pragma unroll
        for (int b = 0; b < 8; ++b) acc[a][b] = (f32x4)0.0f;

    int w = tid >> 6, l = tid & 63;
    int wm = (w >> 1) * 64;                   // 4 M-groups of 64
    int wn = (w & 1) * 128;                   // 2 N-groups of 128
    int fr = l & 15, fg = l >> 4;

    // staging, per wave per buffer: 4 gload16 (A rows 32w..32w+31, B same rows)
    // lane l covers row rS = 32w+16q+(l>>2), stored slot l&3 -> source slot
    // (l&3)^((rS>>1)&3), i.e. source byte col = kc + srcslot*16.
    #define STAGE(buf, kc) do {                                                   \
        _Pragma("unroll")                                                         \
        for (int q = 0; q < 2; ++q) {                                             \
            int r = 32 * w + 16 * q + (l >> 2);                                   \
            int c = (((l & 3) ^ ((r >> 1) & 3)) << 4);                            \
            char* dA = (char*)&smem[buf][0]    + (32 * w + 16 * q) * 64;          \
            char* dB = (char*)&smem[buf][2048] + (32 * w + 16 * q) * 64;          \
            gload16(zq + (size_t)(m0 + r) * D_DIM + (kc) + c, dA);                \
            gload16(eb + (size_t)(n0 + r) * D_DIM + (kc) + c, dB);                \
        }                                                                         \
    } while (0)

    STAGE(0, 0);
    __syncthreads();

    int cur = 0;
    for (int t = 0; t < 8; ++t) {             // K = 512 / BK=64 -> 8 steps
        if (t < 7) STAGE(cur ^ 1, (t + 1) * 64);
        long av[4][2], bv[8][2];
        #pragma unroll
        for (int i = 0; i < 4; ++i) {
            int r = wm + i * 16 + fr;
            int xr = (r >> 1) & 3;
            #pragma unroll
            for (int h = 0; h < 2; ++h) {
                int sl = ((h << 1) + (fg >> 1)) ^ xr;
                av[i][h] = smem[cur][r * 8 + sl * 2 + (fg & 1)];
            }
        }
        #pragma unroll
        for (int j = 0; j < 8; ++j) {
            int r = wn + j * 16 + fr;
            int xr = (r >> 1) & 3;
            #pragma unroll
            for (int h = 0; h < 2; ++h) {
                int sl = ((h << 1) + (fg >> 1)) ^ xr;
                bv[j][h] = smem[cur][2048 + r * 8 + sl * 2 + (fg & 1)];
            }
        }
        __builtin_amdgcn_s_setprio(1);
        #pragma unroll
        for (int mb = 0; mb < 4; ++mb)
            #pragma unroll
            for (int nb = 0; nb < 8; ++nb) {
                acc[mb][nb] = __builtin_amdgcn_mfma_f32_16x16x32_fp8_fp8(
                    av[mb][0], bv[nb][0], acc[mb][nb], 0, 0, 0);
                acc[mb][nb] = __builtin_amdgcn_mfma_f32_16x16x32_fp8_fp8(
                    av[mb][1], bv[nb][1], acc[mb][nb], 0, 0, 0);
            }
        __builtin_amdgcn_s_setprio(0);
        __syncthreads();   // drains vmcnt: buf cur^1 staged; cur reads done
        cur ^= 1;
    }
    #undef STAGE

    // epilogue: dist = (ce+cz) - 2*dot
    #pragma unroll
    for (int mb = 0; mb < 4; ++mb) {
        #pragma unroll
        for (int r = 0; r < 4; ++r) {
            int q = m0 + wm + mb * 16 + fg * 4 + r;
            float czq = cz[q];
            unsigned long long best = ~0ULL;
            #pragma unroll
            for (int nb = 0; nb < 8; ++nb) {
                int j = n0 + wn + nb * 16 + fr;
                float dist = (ce[j] + czq) - 2.0f * acc[mb][nb][r];
                unsigned long long key =
                    ((unsigned long long)__float_as_uint(dist) << 32) | (unsigned)j;
                if (key < best) best = key;
            }
            #pragma unroll
            for (int sft = 1; sft < 16; sft <<= 1) {
                unsigned long long o = __shfl_xor(best, sft, 64);
                if (o < best) best = o;
            }
            if (fr == 0) atomicMin(keys + q, best);
        }
    }
}

// ---- gather + STE output + loss partials + histogram (1 wave per row) ----
__global__ void output_kernel(const float* __restrict__ x, const float* __restrict__ mu,
                              const float* __restrict__ s, const float* __restrict__ emb,
                              const unsigned long long* __restrict__ keys,
                              float* __restrict__ out, float* __restrict__ loss_part,
                              unsigned* __restrict__ hist) {
    int i = blockIdx.x * 4 + (threadIdx.x >> 6);
    int lane = threadIdx.x & 63;
    int n = i >> 10;
    unsigned idx = (unsigned)(keys[i] & 0xFFFFFFFFULL);
    float lsum = 0.f;
    #pragma unroll
    for (int c = 0; c < 2; ++c) {
        int d = c * 256 + lane * 4;
        float4 xv = *(const float4*)&x[(size_t)i * D_DIM + d];
        float4 mv = *(const float4*)&mu[n * D_DIM + d];
        float4 sv = *(const float4*)&s[n * D_DIM + d];
        float4 ev = *(const float4*)&emb[(size_t)idx * D_DIM + d];
        float z0 = (xv.x - mv.x) / sv.x;
        float z1 = (xv.y - mv.y) / sv.y;
        float z2 = (xv.z - mv.z) / sv.z;
        float z3 = (xv.w - mv.w) / sv.w;
        float o0 = ((z0 + (ev.x - z0)) + ev.x) * 0.5f;
        float o1 = ((z1 + (ev.y - z1)) + ev.y) * 0.5f;
        float o2 = ((z2 + (ev.z - z2)) + ev.z) * 0.5f;
        float o3 = ((z3 + (ev.w - z3)) + ev.w) * 0.5f;
        *(float4*)&out[(size_t)i * D_DIM + d] = make_float4(o0, o1, o2, o3);
        lsum += (z0 - ev.x) * (z0 - ev.x) + (z1 - ev.y) * (z1 - ev.y)
              + (z2 - ev.z) * (z2 - ev.z) + (z3 - ev.w) * (z3 - ev.w);
    }
    #pragma unroll
    for (int sft = 32; sft; sft >>= 1) lsum += __shfl_xor(lsum, sft, 64);
    __shared__ float ls[4];
    if (lane == 0) {
        ls[threadIdx.x >> 6] = lsum;
        atomicAdd(&hist[idx], 1u);   // scattered over 2048 bins: cheap
    }
    __syncthreads();
    if (threadIdx.x == 0)
        loss_part[blockIdx.x] = (ls[0] + ls[1]) + (ls[2] + ls[3]);
}

// ---- scalars: loss mean (from partials) + perplexity ----
__global__ void final_kernel(const unsigned* __restrict__ hist,
                             const float* __restrict__ loss_part, float* __restrict__ out) {
    float h = 0.f;
    for (int b = threadIdx.x; b < M_CODES; b += 256) {
        float p = (float)hist[b] * (1.0f / 32768.0f);
        h += p * logf(p + 1e-10f);
    }
    h = block_reduce_sum_256(h);
    float lsum = 0.f;
    for (int b = threadIdx.x; b < NT / 4; b += 256) lsum += loss_part[b];
    lsum = block_reduce_sum_256(lsum);
    if (threadIdx.x == 0) {
        out[TOTAL] = lsum * (1.0f / 16777216.0f);
        out[TOTAL + 1] = expf(-h);
    }
}

extern "C" void kernel_launch(void* const* d_in, const int* in_sizes, int n_in,
                              void* d_out, int out_size, void* d_ws, size_t ws_size,
                              hipStream_t stream) {
    (void)in_sizes; (void)n_in; (void)out_size; (void)ws_size;
    const float* x = (const float*)d_in[0];
    const float* emb = (const float*)d_in[1];
    float* out = (float*)d_out;
    char* ws = (char*)d_ws;
    float* mu   = (float*)(ws + WS_MU);
    float* s    = (float*)(ws + WS_S);
    float* cz   = (float*)(ws + WS_CZ);
    float* ce   = (float*)(ws + WS_CE);
    unsigned long long* keys = (unsigned long long*)(ws + WS_KEYS);
    unsigned char* eb = (unsigned char*)(ws + WS_EB);
    unsigned* hist = (unsigned*)(ws + WS_HIST);
    float* loss_part = (float*)(ws + WS_LPART);
    // z fp8 staged in d_out (16MB), overwritten by output_kernel
    unsigned char* zq = (unsigned char*)d_out;

    (void)hipMemsetAsync(ws + WS_KEYS, 0xFF, 262144, stream);
    (void)hipMemsetAsync(ws + WS_HIST, 0x00, 8192, stream);

    stats_kernel<<<dim3(8, 32), 256, 0, stream>>>(x, mu, s);
    codebook_kernel<<<M_CODES, 256, 0, stream>>>(emb, eb, ce);
    cz_split_kernel<<<NT / 4, 256, 0, stream>>>(x, mu, s, cz, zq);
    gemm_argmin<<<1024, 512, 0, stream>>>(zq, eb, ce, cz, keys);
    output_kernel<<<NT / 4, 256, 0, stream>>>(x, mu, s, emb, keys, out, loss_part, hist);
    final_kernel<<<1, 256, 0, stream>>>(hist, loss_part, out);
}

// Round 13
// 165.063 us; speedup vs baseline: 3.1209x; 1.0245x over previous
//
#include <hip/hip_runtime.h>

#define T_DIM 1024
#define D_DIM 512
#define M_CODES 2048
#define NT 32768            // 32*1024 query rows
#define TOTAL 16777216      // NT*D_DIM

typedef float f32x4 __attribute__((ext_vector_type(4)));
typedef unsigned int u32;

// ---- workspace layout (bytes) ----
#define WS_MU    0                        // 16384 f32
#define WS_S     65536                    // 16384 f32
#define WS_CZ    131072                   // 32768 f32
#define WS_CE    262144                   // 2048 f32
#define WS_KEYS  270336                   // 32768 u64
#define WS_EB    532480                   // 2048*512 fp8 (rounded codebook, 1MB)
#define WS_HIST  (532480 + 1048576)       // 2048 u32
#define WS_LPART (WS_HIST + 8192)         // 8192 f32 per-block loss partials

// async global->LDS, 16B per lane; dst wave-uniform base (HW adds lane*16)
__device__ __forceinline__ void gload16(const void* g, void* l) {
    __builtin_amdgcn_global_load_lds(
        (const __attribute__((address_space(1))) u32*)g,
        (__attribute__((address_space(3))) u32*)l, 16, 0, 0);
}

__device__ __forceinline__ float block_reduce_sum_256(float v) {
    #pragma unroll
    for (int s = 32; s; s >>= 1) v += __shfl_xor(v, s, 64);
    __shared__ float ls[4];
    int w = threadIdx.x >> 6;
    if ((threadIdx.x & 63) == 0) ls[w] = v;
    __syncthreads();
    float r = (ls[0] + ls[1]) + (ls[2] + ls[3]);
    __syncthreads();
    return r;
}

// pack 4 floats -> 4 fp8 e4m3 (OCP, RNE)
__device__ __forceinline__ u32 pk_fp8x4(float a, float b, float c, float d) {
    u32 w = __builtin_amdgcn_cvt_pk_fp8_f32(a, b, 0, false);
    w = __builtin_amdgcn_cvt_pk_fp8_f32(c, d, w, true);
    return w;
}

// K-layout permutation baked at pack time: within each 32B k-block of row r,
// 8B sub-slot s stores orig sub-slot s ^ ((r>>2)&3). Read side XORs the same
// -> cancels (MFMA inputs identical), and b64 fragment reads become
// bank-conflict-free: bank = 8*(fr&3) + 2*(fg^((fr>>2)&3)) covers all 32.
__device__ __forceinline__ int pk_dest(int d, int row) {
    return (d & ~31) | ((((d >> 3) & 3) ^ ((row >> 2) & 3)) << 3) | (d & 7);
}

// ---- instance-norm stats over T per (n,d): mu, s=std+eps ----
__global__ void stats_kernel(const float* __restrict__ x,
                             float* __restrict__ mu_o, float* __restrict__ s_o) {
    int n = blockIdx.y;
    int lane = threadIdx.x & 63;
    int d = blockIdx.x * 64 + lane;
    int tg = threadIdx.x >> 6;
    const float* xp = x + (size_t)n * (T_DIM * D_DIM) + d;
    float sum = 0.f, sq = 0.f;
    int t0 = tg * 256;
    for (int it = 0; it < 256; ++it) {
        float v = xp[(size_t)(t0 + it) * D_DIM];
        sum += v; sq += v * v;
    }
    __shared__ float ssum[4][64], ssq[4][64];
    ssum[tg][lane] = sum;
    ssq[tg][lane] = sq;
    __syncthreads();
    if (threadIdx.x < 64) {
        int l = threadIdx.x;
        float s1 = (ssum[0][l] + ssum[1][l]) + (ssum[2][l] + ssum[3][l]);
        float q1 = (ssq[0][l] + ssq[1][l]) + (ssq[2][l] + ssq[3][l]);
        float mu = s1 * (1.0f / 1024.0f);
        float var = (q1 - 1024.0f * mu * mu) * (1.0f / 1023.0f);
        var = fmaxf(var, 0.0f);
        float sd = sqrtf(var) + 1e-5f;
        int nd = n * D_DIM + blockIdx.x * 64 + l;
        mu_o[nd] = mu; s_o[nd] = sd;
    }
}

// ---- codebook prep: emb_n -> fp8 (K-permuted), ce = exact sum(emb_n^2) ----
__global__ void codebook_kernel(const float* __restrict__ emb,
                                unsigned char* __restrict__ eb, float* __restrict__ ce) {
    int j = blockIdx.x;
    int d = threadIdx.x * 2;
    float2 e = *(const float2*)&emb[(size_t)j * D_DIM + d];
    float sq = e.x * e.x + e.y * e.y;
    float norm2 = block_reduce_sum_256(sq);
    float den = sqrtf(norm2) + 1e-4f;
    float en0 = e.x / den, en1 = e.y / den;
    u32 w = __builtin_amdgcn_cvt_pk_fp8_f32(en0, en1, 0, false);
    *(unsigned short*)&eb[(size_t)j * D_DIM + pk_dest(d, j)] =
        (unsigned short)(w & 0xFFFF);
    float cep = en0 * en0 + en1 * en1;      // ce from EXACT emb_n (matches ref)
    float cesum = block_reduce_sum_256(cep);
    if (threadIdx.x == 0) ce[j] = cesum;
}

// ---- z = (x-mu)/s exact fp32; store z as fp8 (K-permuted); cz exact ----
__global__ void cz_split_kernel(const float* __restrict__ x, const float* __restrict__ mu,
                                const float* __restrict__ s, float* __restrict__ cz,
                                unsigned char* __restrict__ zq) {
    int i = blockIdx.x * 4 + (threadIdx.x >> 6);
    int lane = threadIdx.x & 63;
    int n = i >> 10;
    const float* xp = x + (size_t)i * D_DIM;
    const float* mp = mu + n * D_DIM;
    const float* sp = s + n * D_DIM;
    float acc = 0.f;
    #pragma unroll
    for (int c = 0; c < 2; ++c) {
        int d = c * 256 + lane * 4;
        float4 xv = *(const float4*)&xp[d];
        float4 mv = *(const float4*)&mp[d];
        float4 sv = *(const float4*)&sp[d];
        float z0 = (xv.x - mv.x) / sv.x;
        float z1 = (xv.y - mv.y) / sv.y;
        float z2 = (xv.z - mv.z) / sv.z;
        float z3 = (xv.w - mv.w) / sv.w;
        *(u32*)&zq[(size_t)i * D_DIM + pk_dest(d, i)] = pk_fp8x4(z0, z1, z2, z3);
        acc += z0 * z0 + z1 * z1 + z2 * z2 + z3 * z3;   // cz stays exact
    }
    #pragma unroll
    for (int sft = 32; sft; sft >>= 1) acc += __shfl_xor(acc, sft, 64);
    if (lane == 0) cz[i] = acc;
}

// ---- MFMA fp8 GEMM + argmin, 4-buffer counted-vmcnt pipeline ----
// Tile 256x256, BK=32 (16 steps x 16KB), 8 waves (4Mx2N), 4 LDS bufs (64KB),
// 2 blocks/CU. Loads for step t+1 issued at step t-2 -> 3-step latency
// budget; vmcnt(4) at steady-state barriers (2 gloads/wave/step).
// LDS buf (u64): A[1024] | B[1024]. b64 frag reads conflict-free via baked
// K-permutation (see pk_dest).
__global__ __launch_bounds__(512, 2) void gemm_argmin(
    const unsigned char* __restrict__ zq, const unsigned char* __restrict__ eb,
    const float* __restrict__ ce, const float* __restrict__ cz,
    unsigned long long* __restrict__ keys) {
    __shared__ long smem[4][2048];
    int tid = threadIdx.x;
    int bid = blockIdx.x;
    // XCD-chunked (1024%8==0): per XCD n varies fastest -> A-tile L2 reuse.
    int swz = (bid & 7) * 128 + (bid >> 3);
    int n0 = (swz & 7) * 256;                 // code tile (8 n-tiles)
    int m0 = (swz >> 3) * 256;                // query-row tile (128 m-tiles)

    f32x4 acc[4][8];
    #pragma unroll
    for (int a = 0; a < 4; ++a)
        #pragma unroll
        for (int b = 0; b < 8; ++b) acc[a][b] = (f32x4)0.0f;

    int w = tid >> 6, l = tid & 63;
    int wm = (w >> 1) * 64;                   // 4 M-groups of 64
    int wn = (w & 1) * 128;                   // 2 N-groups of 128
    int fr = l & 15, fg = l >> 4;
    int xfg = fg ^ ((fr >> 2) & 3);           // read-side XOR (cancels packing)

    // staging: per wave per step 2 gload16 (A rows 32w..32w+31, B same rows);
    // lane l covers row 32w+(l>>1), 16B-half (l&1). Data is pre-permuted, so
    // both source and LDS are linear.
    int rS = 32 * w + (l >> 1);
    int hS = (l & 1) * 16;
    size_t srcA = (size_t)(m0 + rS) * D_DIM + hS;
    size_t srcB = (size_t)(n0 + rS) * D_DIM + hS;

    #define STAGE(buf, t) do {                                                    \
        gload16(zq + srcA + (t) * 32, &smem[buf][w * 128]);                       \
        gload16(eb + srcB + (t) * 32, &smem[buf][1024 + w * 128]);                \
    } while (0)

    STAGE(0, 0);
    STAGE(1, 1);
    STAGE(2, 2);
    asm volatile("s_waitcnt vmcnt(4)" ::: "memory");   // buf0's 2 landed
    __builtin_amdgcn_s_barrier();
    __builtin_amdgcn_sched_barrier(0);

    for (int t = 0; t < 16; ++t) {
        int cur = t & 3;
        if (t <= 12) STAGE((t + 3) & 3, t + 3);
        long av[4], bv[8];
        #pragma unroll
        for (int i = 0; i < 4; ++i)
            av[i] = smem[cur][(wm + i * 16 + fr) * 4 + xfg];
        #pragma unroll
        for (int j = 0; j < 8; ++j)
            bv[j] = smem[cur][1024 + (wn + j * 16 + fr) * 4 + xfg];
        __builtin_amdgcn_s_setprio(1);
        #pragma unroll
        for (int mb = 0; mb < 4; ++mb)
            #pragma unroll
            for (int nb = 0; nb < 8; ++nb)
                acc[mb][nb] = __builtin_amdgcn_mfma_f32_16x16x32_fp8_fp8(
                    av[mb], bv[nb], acc[mb][nb], 0, 0, 0);
        __builtin_amdgcn_s_setprio(0);
        if (t < 15) {
            // counted wait: buf t+1 landed; newer stages stay in flight
            if (t <= 12)      asm volatile("s_waitcnt vmcnt(4)" ::: "memory");
            else if (t == 13) asm volatile("s_waitcnt vmcnt(2)" ::: "memory");
            else              asm volatile("s_waitcnt vmcnt(0)" ::: "memory");
            __builtin_amdgcn_s_barrier();
            __builtin_amdgcn_sched_barrier(0);
        }
    }
    #undef STAGE

    // epilogue: dist = (ce+cz) - 2*dot
    #pragma unroll
    for (int mb = 0; mb < 4; ++mb) {
        #pragma unroll
        for (int r = 0; r < 4; ++r) {
            int q = m0 + wm + mb * 16 + fg * 4 + r;
            float czq = cz[q];
            unsigned long long best = ~0ULL;
            #pragma unroll
            for (int nb = 0; nb < 8; ++nb) {
                int j = n0 + wn + nb * 16 + fr;
                float dist = (ce[j] + czq) - 2.0f * acc[mb][nb][r];
                unsigned long long key =
                    ((unsigned long long)__float_as_uint(dist) << 32) | (unsigned)j;
                if (key < best) best = key;
            }
            #pragma unroll
            for (int sft = 1; sft < 16; sft <<= 1) {
                unsigned long long o = __shfl_xor(best, sft, 64);
                if (o < best) best = o;
            }
            if (fr == 0) atomicMin(keys + q, best);
        }
    }
}

// ---- gather + STE output + loss partials + histogram (1 wave per row) ----
__global__ void output_kernel(const float* __restrict__ x, const float* __restrict__ mu,
                              const float* __restrict__ s, const float* __restrict__ emb,
                              const unsigned long long* __restrict__ keys,
                              float* __restrict__ out, float* __restrict__ loss_part,
                              unsigned* __restrict__ hist) {
    int i = blockIdx.x * 4 + (threadIdx.x >> 6);
    int lane = threadIdx.x & 63;
    int n = i >> 10;
    unsigned idx = (unsigned)(keys[i] & 0xFFFFFFFFULL);
    float lsum = 0.f;
    #pragma unroll
    for (int c = 0; c < 2; ++c) {
        int d = c * 256 + lane * 4;
        float4 xv = *(const float4*)&x[(size_t)i * D_DIM + d];
        float4 mv = *(const float4*)&mu[n * D_DIM + d];
        float4 sv = *(const float4*)&s[n * D_DIM + d];
        float4 ev = *(const float4*)&emb[(size_t)idx * D_DIM + d];
        float z0 = (xv.x - mv.x) / sv.x;
        float z1 = (xv.y - mv.y) / sv.y;
        float z2 = (xv.z - mv.z) / sv.z;
        float z3 = (xv.w - mv.w) / sv.w;
        float o0 = ((z0 + (ev.x - z0)) + ev.x) * 0.5f;
        float o1 = ((z1 + (ev.y - z1)) + ev.y) * 0.5f;
        float o2 = ((z2 + (ev.z - z2)) + ev.z) * 0.5f;
        float o3 = ((z3 + (ev.w - z3)) + ev.w) * 0.5f;
        *(float4*)&out[(size_t)i * D_DIM + d] = make_float4(o0, o1, o2, o3);
        lsum += (z0 - ev.x) * (z0 - ev.x) + (z1 - ev.y) * (z1 - ev.y)
              + (z2 - ev.z) * (z2 - ev.z) + (z3 - ev.w) * (z3 - ev.w);
    }
    #pragma unroll
    for (int sft = 32; sft; sft >>= 1) lsum += __shfl_xor(lsum, sft, 64);
    __shared__ float ls[4];
    if (lane == 0) {
        ls[threadIdx.x >> 6] = lsum;
        atomicAdd(&hist[idx], 1u);   // scattered over 2048 bins: cheap
    }
    __syncthreads();
    if (threadIdx.x == 0)
        loss_part[blockIdx.x] = (ls[0] + ls[1]) + (ls[2] + ls[3]);
}

// ---- scalars: loss mean (from partials) + perplexity ----
__global__ void final_kernel(const unsigned* __restrict__ hist,
                             const float* __restrict__ loss_part, float* __restrict__ out) {
    float h = 0.f;
    for (int b = threadIdx.x; b < M_CODES; b += 256) {
        float p = (float)hist[b] * (1.0f / 32768.0f);
        h += p * logf(p + 1e-10f);
    }
    h = block_reduce_sum_256(h);
    float lsum = 0.f;
    for (int b = threadIdx.x; b < NT / 4; b += 256) lsum += loss_part[b];
    lsum = block_reduce_sum_256(lsum);
    if (threadIdx.x == 0) {
        out[TOTAL] = lsum * (1.0f / 16777216.0f);
        out[TOTAL + 1] = expf(-h);
    }
}

extern "C" void kernel_launch(void* const* d_in, const int* in_sizes, int n_in,
                              void* d_out, int out_size, void* d_ws, size_t ws_size,
                              hipStream_t stream) {
    (void)in_sizes; (void)n_in; (void)out_size; (void)ws_size;
    const float* x = (const float*)d_in[0];
    const float* emb = (const float*)d_in[1];
    float* out = (float*)d_out;
    char* ws = (char*)d_ws;
    float* mu   = (float*)(ws + WS_MU);
    float* s    = (float*)(ws + WS_S);
    float* cz   = (float*)(ws + WS_CZ);
    float* ce   = (float*)(ws + WS_CE);
    unsigned long long* keys = (unsigned long long*)(ws + WS_KEYS);
    unsigned char* eb = (unsigned char*)(ws + WS_EB);
    unsigned* hist = (unsigned*)(ws + WS_HIST);
    float* loss_part = (float*)(ws + WS_LPART);
    // z fp8 staged in d_out (16MB), overwritten by output_kernel
    unsigned char* zq = (unsigned char*)d_out;

    (void)hipMemsetAsync(ws + WS_KEYS, 0xFF, 262144, stream);
    (void)hipMemsetAsync(ws + WS_HIST, 0x00, 8192, stream);

    stats_kernel<<<dim3(8, 32), 256, 0, stream>>>(x, mu, s);
    codebook_kernel<<<M_CODES, 256, 0, stream>>>(emb, eb, ce);
    cz_split_kernel<<<NT / 4, 256, 0, stream>>>(x, mu, s, cz, zq);
    gemm_argmin<<<1024, 512, 0, stream>>>(zq, eb, ce, cz, keys);
    output_kernel<<<NT / 4, 256, 0, stream>>>(x, mu, s, emb, keys, out, loss_part, hist);
    final_kernel<<<1, 256, 0, stream>>>(hist, loss_part, out);
}

// Round 15
// 163.420 us; speedup vs baseline: 3.1523x; 1.0101x over previous
//
#include <hip/hip_runtime.h>

#define T_DIM 1024
#define D_DIM 512
#define M_CODES 2048
#define NT 32768            // 32*1024 query rows
#define TOTAL 16777216      // NT*D_DIM

typedef float f32x4 __attribute__((ext_vector_type(4)));
typedef unsigned int u32;
typedef unsigned long long u64;

// ---- workspace layout (bytes) ----
#define WS_MU    0                        // 16384 f32
#define WS_S     65536                    // 16384 f32
#define WS_CE    131072                   // 2048 f32
#define WS_KEYS  139264                   // 32768 u64
#define WS_EB    401408                   // 2048*512 fp8 (rounded codebook, 1MB)
#define WS_HIST  (401408 + 1048576)       // 2048 u32
#define WS_LPART (WS_HIST + 8192)         // 8192 f32 per-block loss partials

// async global->LDS, 16B per lane; dst wave-uniform base (HW adds lane*16)
__device__ __forceinline__ void gload16(const void* g, void* l) {
    __builtin_amdgcn_global_load_lds(
        (const __attribute__((address_space(1))) u32*)g,
        (__attribute__((address_space(3))) u32*)l, 16, 0, 0);
}

__device__ __forceinline__ float block_reduce_sum_256(float v) {
    #pragma unroll
    for (int s = 32; s; s >>= 1) v += __shfl_xor(v, s, 64);
    __shared__ float ls[4];
    int w = threadIdx.x >> 6;
    if ((threadIdx.x & 63) == 0) ls[w] = v;
    __syncthreads();
    float r = (ls[0] + ls[1]) + (ls[2] + ls[3]);
    __syncthreads();
    return r;
}

// pack 4 floats -> 4 fp8 e4m3 (OCP, RNE)
__device__ __forceinline__ u32 pk_fp8x4(float a, float b, float c, float d) {
    u32 w = __builtin_amdgcn_cvt_pk_fp8_f32(a, b, 0, false);
    w = __builtin_amdgcn_cvt_pk_fp8_f32(c, d, w, true);
    return w;
}

// monotone float->uint (total order incl. negatives)
__device__ __forceinline__ u32 mono(float f) {
    u32 u = __float_as_uint(f);
    return u ^ (0x80000000u | (u32)((int)u >> 31));
}

// K-layout permutation baked at pack time: within each 32B k-block of row r,
// 8B sub-slot s stores orig sub-slot s ^ ((r>>2)&3). Read side XORs the same
// -> cancels (MFMA inputs identical), and b64 fragment reads are
// bank-conflict-free (verified R13: SQ_LDS_BANK_CONFLICT = 0).
__device__ __forceinline__ int pk_dest(int d, int row) {
    return (d & ~31) | ((((d >> 3) & 3) ^ ((row >> 2) & 3)) << 3) | (d & 7);
}

// ---- instance-norm stats over T per (n,d): mu, s=std+eps ----
__global__ void stats_kernel(const float* __restrict__ x,
                             float* __restrict__ mu_o, float* __restrict__ s_o) {
    int n = blockIdx.y;
    int lane = threadIdx.x & 63;
    int d = blockIdx.x * 64 + lane;
    int tg = threadIdx.x >> 6;
    const float* xp = x + (size_t)n * (T_DIM * D_DIM) + d;
    float sum = 0.f, sq = 0.f;
    int t0 = tg * 256;
    for (int it = 0; it < 256; ++it) {
        float v = xp[(size_t)(t0 + it) * D_DIM];
        sum += v; sq += v * v;
    }
    __shared__ float ssum[4][64], ssq[4][64];
    ssum[tg][lane] = sum;
    ssq[tg][lane] = sq;
    __syncthreads();
    if (threadIdx.x < 64) {
        int l = threadIdx.x;
        float s1 = (ssum[0][l] + ssum[1][l]) + (ssum[2][l] + ssum[3][l]);
        float q1 = (ssq[0][l] + ssq[1][l]) + (ssq[2][l] + ssq[3][l]);
        float mu = s1 * (1.0f / 1024.0f);
        float var = (q1 - 1024.0f * mu * mu) * (1.0f / 1023.0f);
        var = fmaxf(var, 0.0f);
        float sd = sqrtf(var) + 1e-5f;
        int nd = n * D_DIM + blockIdx.x * 64 + l;
        mu_o[nd] = mu; s_o[nd] = sd;
    }
}

// ---- codebook prep: emb_n -> fp8 (K-permuted), ce = exact sum(emb_n^2) ----
__global__ void codebook_kernel(const float* __restrict__ emb,
                                unsigned char* __restrict__ eb, float* __restrict__ ce) {
    int j = blockIdx.x;
    int d = threadIdx.x * 2;
    float2 e = *(const float2*)&emb[(size_t)j * D_DIM + d];
    float sq = e.x * e.x + e.y * e.y;
    float norm2 = block_reduce_sum_256(sq);
    float den = sqrtf(norm2) + 1e-4f;
    float en0 = e.x / den, en1 = e.y / den;
    u32 w = __builtin_amdgcn_cvt_pk_fp8_f32(en0, en1, 0, false);
    *(unsigned short*)&eb[(size_t)j * D_DIM + pk_dest(d, j)] =
        (unsigned short)(w & 0xFFFF);
    float cep = en0 * en0 + en1 * en1;      // ce from EXACT emb_n (matches ref)
    float cesum = block_reduce_sum_256(cep);
    if (threadIdx.x == 0) ce[j] = cesum;
}

// ---- z = (x-mu)/s exact fp32; store z as fp8 (K-permuted). No cz needed:
// cz is constant over j -> argmin-invariant. ----
__global__ void pack_kernel(const float* __restrict__ x, const float* __restrict__ mu,
                            const float* __restrict__ s, unsigned char* __restrict__ zq) {
    int i = blockIdx.x * 4 + (threadIdx.x >> 6);
    int lane = threadIdx.x & 63;
    int n = i >> 10;
    const float* xp = x + (size_t)i * D_DIM;
    const float* mp = mu + n * D_DIM;
    const float* sp = s + n * D_DIM;
    #pragma unroll
    for (int c = 0; c < 2; ++c) {
        int d = c * 256 + lane * 4;
        float4 xv = *(const float4*)&xp[d];
        float4 mv = *(const float4*)&mp[d];
        float4 sv = *(const float4*)&sp[d];
        float z0 = (xv.x - mv.x) / sv.x;
        float z1 = (xv.y - mv.y) / sv.y;
        float z2 = (xv.z - mv.z) / sv.z;
        float z3 = (xv.w - mv.w) / sv.w;
        *(u32*)&zq[(size_t)i * D_DIM + pk_dest(d, i)] = pk_fp8x4(z0, z1, z2, z3);
    }
}

// ---- MFMA fp8 GEMM + argmin, 4-buffer counted-vmcnt pipeline (R13) ----
// Tile 256x256, BK=32 (16 steps x 16KB), 8 waves (4Mx2N), 4 LDS bufs (64KB),
// 2 blocks/CU. vmcnt(4) steady-state; b64 frag reads conflict-free (pk_dest).
// Epilogue keys on (ce_j - 2*dot) via monotone bit-mapping (cz dropped).
__global__ __launch_bounds__(512, 2) void gemm_argmin(
    const unsigned char* __restrict__ zq, const unsigned char* __restrict__ eb,
    const float* __restrict__ ce, u64* __restrict__ keys) {
    __shared__ long smem[4][2048];
    int tid = threadIdx.x;
    int bid = blockIdx.x;
    // XCD-chunked (1024%8==0): per XCD n varies fastest -> A-tile L2 reuse.
    int swz = (bid & 7) * 128 + (bid >> 3);
    int n0 = (swz & 7) * 256;                 // code tile (8 n-tiles)
    int m0 = (swz >> 3) * 256;                // query-row tile (128 m-tiles)

    f32x4 acc[4][8];
    #pragma unroll
    for (int a = 0; a < 4; ++a)
        #pragma unroll
        for (int b = 0; b < 8; ++b) acc[a][b] = (f32x4)0.0f;

    int w = tid >> 6, l = tid & 63;
    int wm = (w >> 1) * 64;                   // 4 M-groups of 64
    int wn = (w & 1) * 128;                   // 2 N-groups of 128
    int fr = l & 15, fg = l >> 4;
    int xfg = fg ^ ((fr >> 2) & 3);           // read-side XOR (cancels packing)

    int rS = 32 * w + (l >> 1);
    int hS = (l & 1) * 16;
    size_t srcA = (size_t)(m0 + rS) * D_DIM + hS;
    size_t srcB = (size_t)(n0 + rS) * D_DIM + hS;

    #define STAGE(buf, t) do {                                                    \
        gload16(zq + srcA + (t) * 32, &smem[buf][w * 128]);                       \
        gload16(eb + srcB + (t) * 32, &smem[buf][1024 + w * 128]);                \
    } while (0)

    STAGE(0, 0);
    STAGE(1, 1);
    STAGE(2, 2);
    asm volatile("s_waitcnt vmcnt(4)" ::: "memory");   // buf0's 2 landed
    __builtin_amdgcn_s_barrier();
    __builtin_amdgcn_sched_barrier(0);

    for (int t = 0; t < 16; ++t) {
        int cur = t & 3;
        if (t <= 12) STAGE((t + 3) & 3, t + 3);
        long av[4], bv[8];
        #pragma unroll
        for (int i = 0; i < 4; ++i)
            av[i] = smem[cur][(wm + i * 16 + fr) * 4 + xfg];
        #pragma unroll
        for (int j = 0; j < 8; ++j)
            bv[j] = smem[cur][1024 + (wn + j * 16 + fr) * 4 + xfg];
        __builtin_amdgcn_s_setprio(1);
        #pragma unroll
        for (int mb = 0; mb < 4; ++mb)
            #pragma unroll
            for (int nb = 0; nb < 8; ++nb)
                acc[mb][nb] = __builtin_amdgcn_mfma_f32_16x16x32_fp8_fp8(
                    av[mb], bv[nb], acc[mb][nb], 0, 0, 0);
        __builtin_amdgcn_s_setprio(0);
        if (t < 15) {
            if (t <= 12)      asm volatile("s_waitcnt vmcnt(4)" ::: "memory");
            else if (t == 13) asm volatile("s_waitcnt vmcnt(2)" ::: "memory");
            else              asm volatile("s_waitcnt vmcnt(0)" ::: "memory");
            __builtin_amdgcn_s_barrier();
            __builtin_amdgcn_sched_barrier(0);
        }
    }
    #undef STAGE

    // epilogue: argmin of (ce_j - 2*dot)  [cz dropped: constant over j]
    #pragma unroll
    for (int mb = 0; mb < 4; ++mb) {
        #pragma unroll
        for (int r = 0; r < 4; ++r) {
            int q = m0 + wm + mb * 16 + fg * 4 + r;
            u64 best = ~0ULL;
            #pragma unroll
            for (int nb = 0; nb < 8; ++nb) {
                int j = n0 + wn + nb * 16 + fr;
                float dist = ce[j] - 2.0f * acc[mb][nb][r];
                u64 key = ((u64)mono(dist) << 32) | (unsigned)j;
                if (key < best) best = key;
            }
            #pragma unroll
            for (int sft = 1; sft < 16; sft <<= 1) {
                u64 o = __shfl_xor(best, sft, 64);
                if (o < best) best = o;
            }
            if (fr == 0) atomicMin(keys + q, best);
        }
    }
}

// ---- gather + STE output + loss partials + histogram (1 wave per row) ----
// Reads x/mu/s (NOT zq: out writes alias zq's d_out staging -> cross-block
// race, R14 lesson). Exact-fp32 z for output and loss.
__global__ void output_kernel(const float* __restrict__ x, const float* __restrict__ mu,
                              const float* __restrict__ s, const float* __restrict__ emb,
                              const u64* __restrict__ keys,
                              float* __restrict__ out, float* __restrict__ loss_part,
                              unsigned* __restrict__ hist) {
    int i = blockIdx.x * 4 + (threadIdx.x >> 6);
    int lane = threadIdx.x & 63;
    int n = i >> 10;
    unsigned idx = (unsigned)(keys[i] & 0xFFFFFFFFULL);
    float lsum = 0.f;
    #pragma unroll
    for (int c = 0; c < 2; ++c) {
        int d = c * 256 + lane * 4;
        float4 xv = *(const float4*)&x[(size_t)i * D_DIM + d];
        float4 mv = *(const float4*)&mu[n * D_DIM + d];
        float4 sv = *(const float4*)&s[n * D_DIM + d];
        float4 ev = *(const float4*)&emb[(size_t)idx * D_DIM + d];
        float z0 = (xv.x - mv.x) / sv.x;
        float z1 = (xv.y - mv.y) / sv.y;
        float z2 = (xv.z - mv.z) / sv.z;
        float z3 = (xv.w - mv.w) / sv.w;
        float o0 = ((z0 + (ev.x - z0)) + ev.x) * 0.5f;
        float o1 = ((z1 + (ev.y - z1)) + ev.y) * 0.5f;
        float o2 = ((z2 + (ev.z - z2)) + ev.z) * 0.5f;
        float o3 = ((z3 + (ev.w - z3)) + ev.w) * 0.5f;
        *(float4*)&out[(size_t)i * D_DIM + d] = make_float4(o0, o1, o2, o3);
        lsum += (z0 - ev.x) * (z0 - ev.x) + (z1 - ev.y) * (z1 - ev.y)
              + (z2 - ev.z) * (z2 - ev.z) + (z3 - ev.w) * (z3 - ev.w);
    }
    #pragma unroll
    for (int sft = 32; sft; sft >>= 1) lsum += __shfl_xor(lsum, sft, 64);
    __shared__ float ls[4];
    if (lane == 0) {
        ls[threadIdx.x >> 6] = lsum;
        atomicAdd(&hist[idx], 1u);   // scattered over 2048 bins: cheap
    }
    __syncthreads();
    if (threadIdx.x == 0)
        loss_part[blockIdx.x] = (ls[0] + ls[1]) + (ls[2] + ls[3]);
}

// ---- scalars: loss mean (from partials) + perplexity ----
__global__ void final_kernel(const unsigned* __restrict__ hist,
                             const float* __restrict__ loss_part, float* __restrict__ out) {
    float h = 0.f;
    for (int b = threadIdx.x; b < M_CODES; b += 256) {
        float p = (float)hist[b] * (1.0f / 32768.0f);
        h += p * logf(p + 1e-10f);
    }
    h = block_reduce_sum_256(h);
    float lsum = 0.f;
    for (int b = threadIdx.x; b < NT / 4; b += 256) lsum += loss_part[b];
    lsum = block_reduce_sum_256(lsum);
    if (threadIdx.x == 0) {
        out[TOTAL] = lsum * (1.0f / 16777216.0f);
        out[TOTAL + 1] = expf(-h);
    }
}

extern "C" void kernel_launch(void* const* d_in, const int* in_sizes, int n_in,
                              void* d_out, int out_size, void* d_ws, size_t ws_size,
                              hipStream_t stream) {
    (void)in_sizes; (void)n_in; (void)out_size; (void)ws_size;
    const float* x = (const float*)d_in[0];
    const float* emb = (const float*)d_in[1];
    float* out = (float*)d_out;
    char* ws = (char*)d_ws;
    float* mu   = (float*)(ws + WS_MU);
    float* s    = (float*)(ws + WS_S);
    float* ce   = (float*)(ws + WS_CE);
    u64* keys = (u64*)(ws + WS_KEYS);
    unsigned char* eb = (unsigned char*)(ws + WS_EB);
    unsigned* hist = (unsigned*)(ws + WS_HIST);
    float* loss_part = (float*)(ws + WS_LPART);
    // z fp8 staged in d_out (16MB); output_kernel does NOT read it (race-safe)
    unsigned char* zq = (unsigned char*)d_out;

    (void)hipMemsetAsync(ws + WS_KEYS, 0xFF, 262144, stream);
    (void)hipMemsetAsync(ws + WS_HIST, 0x00, 8192, stream);

    stats_kernel<<<dim3(8, 32), 256, 0, stream>>>(x, mu, s);
    codebook_kernel<<<M_CODES, 256, 0, stream>>>(emb, eb, ce);
    pack_kernel<<<NT / 4, 256, 0, stream>>>(x, mu, s, zq);
    gemm_argmin<<<1024, 512, 0, stream>>>(zq, eb, ce, keys);
    output_kernel<<<NT / 4, 256, 0, stream>>>(x, mu, s, emb, keys, out, loss_part, hist);
    final_kernel<<<1, 256, 0, stream>>>(hist, loss_part, out);
}